// Round 1
// baseline (133.519 us; speedup 1.0000x reference)
//
#include <hip/hip_runtime.h>

#define NROWS 4096
#define NCOLS 10000
#define DDIM  512

// ---------- reduction helpers ----------
__device__ __forceinline__ float wave_reduce_sum(float v) {
    #pragma unroll
    for (int o = 32; o > 0; o >>= 1) v += __shfl_down(v, o, 64);
    return v;
}

// ---------- kernel 1: per-row BCE partials ----------
// For each row i and each logits tensor L:
//   c_L(i) = dot(L_i, x_i) - log(sum_j exp(L_ij)) * sum_j x_ij
// BCE_L = -(1/(B*V)) * sum_i c_L(i)
__global__ __launch_bounds__(256) void bce_rows_kernel(
    const float4* __restrict__ merged,  // recon_x
    const float4* __restrict__ rec,     // logits_rec
    const float4* __restrict__ text,    // logits_text
    const float4* __restrict__ xr,      // x
    float* __restrict__ cm, float* __restrict__ ct, float* __restrict__ cr)
{
    const int row = blockIdx.x;
    const int nvec = NCOLS / 4;              // 2500 float4 per row
    const size_t base = (size_t)row * nvec;

    float se_m = 0.f, se_t = 0.f, se_r = 0.f;   // sum exp
    float d_m = 0.f, d_t = 0.f, d_r = 0.f;      // dot with x
    float sx = 0.f;                             // sum x

    for (int i = threadIdx.x; i < nvec; i += 256) {
        const float4 xv = xr[base + i];
        const float4 mv = merged[base + i];
        const float4 tv = text[base + i];
        const float4 rv = rec[base + i];

        se_m += __expf(mv.x) + __expf(mv.y) + __expf(mv.z) + __expf(mv.w);
        se_t += __expf(tv.x) + __expf(tv.y) + __expf(tv.z) + __expf(tv.w);
        se_r += __expf(rv.x) + __expf(rv.y) + __expf(rv.z) + __expf(rv.w);

        d_m += mv.x * xv.x + mv.y * xv.y + mv.z * xv.z + mv.w * xv.w;
        d_t += tv.x * xv.x + tv.y * xv.y + tv.z * xv.z + tv.w * xv.w;
        d_r += rv.x * xv.x + rv.y * xv.y + rv.z * xv.z + rv.w * xv.w;

        sx += xv.x + xv.y + xv.z + xv.w;
    }

    // wave-level reduce, then cross-wave via LDS
    __shared__ float sm[4][7];
    float vals[7] = {se_m, se_t, se_r, d_m, d_t, d_r, sx};
    #pragma unroll
    for (int k = 0; k < 7; ++k) vals[k] = wave_reduce_sum(vals[k]);

    const int wave = threadIdx.x >> 6;
    const int lane = threadIdx.x & 63;
    if (lane == 0) {
        #pragma unroll
        for (int k = 0; k < 7; ++k) sm[wave][k] = vals[k];
    }
    __syncthreads();

    if (threadIdx.x == 0) {
        float t[7];
        #pragma unroll
        for (int k = 0; k < 7; ++k)
            t[k] = sm[0][k] + sm[1][k] + sm[2][k] + sm[3][k];
        const float sumx = t[6];
        cm[row] = t[3] - __logf(t[0]) * sumx;
        ct[row] = t[4] - __logf(t[1]) * sumx;
        cr[row] = t[5] - __logf(t[2]) * sumx;
    }
}

// ---------- kernel 2: KLD + Wasserstein elementwise partials ----------
__global__ __launch_bounds__(256) void kld_wass_kernel(
    const float4* __restrict__ mu, const float4* __restrict__ lv,
    const float4* __restrict__ pmu, const float4* __restrict__ plv,
    float* __restrict__ k1o, float* __restrict__ k2o, float* __restrict__ wo)
{
    const int nvec = NROWS * DDIM / 4;   // 524288
    float k1 = 0.f, k2 = 0.f, wacc = 0.f;

    for (int i = blockIdx.x * 256 + threadIdx.x; i < nvec; i += gridDim.x * 256) {
        const float4 m  = mu[i];
        const float4 l  = lv[i];
        const float4 pm = pmu[i];
        const float4 pl = plv[i];

        #define KW_COMP(c)                                              \
        {                                                               \
            const float e1 = __expf(l.c);                               \
            const float e2 = __expf(pl.c);                              \
            k1 += 1.f + l.c - m.c * m.c - e1;                           \
            k2 += 1.f + pl.c - pm.c * pm.c - e2;                        \
            const float dm = m.c - pm.c;                                \
            wacc += dm * dm + e1 + e2 - 2.f * __expf(0.5f * (l.c + pl.c)); \
        }
        KW_COMP(x) KW_COMP(y) KW_COMP(z) KW_COMP(w)
        #undef KW_COMP
    }

    __shared__ float sm[4][3];
    k1 = wave_reduce_sum(k1);
    k2 = wave_reduce_sum(k2);
    wacc = wave_reduce_sum(wacc);
    const int wave = threadIdx.x >> 6;
    const int lane = threadIdx.x & 63;
    if (lane == 0) { sm[wave][0] = k1; sm[wave][1] = k2; sm[wave][2] = wacc; }
    __syncthreads();
    if (threadIdx.x == 0) {
        k1o[blockIdx.x] = sm[0][0] + sm[1][0] + sm[2][0] + sm[3][0];
        k2o[blockIdx.x] = sm[0][1] + sm[1][1] + sm[2][1] + sm[3][1];
        wo[blockIdx.x]  = sm[0][2] + sm[1][2] + sm[2][2] + sm[3][2];
    }
}

// ---------- kernel 3: finalize ----------
__global__ __launch_bounds__(256) void finalize_kernel(
    const float* __restrict__ cm, const float* __restrict__ ct,
    const float* __restrict__ cr, const float* __restrict__ k1p,
    const float* __restrict__ k2p, const float* __restrict__ wp,
    int nk, float* __restrict__ out)
{
    float sm_ = 0.f, st_ = 0.f, sr_ = 0.f;
    for (int i = threadIdx.x; i < NROWS; i += 256) {
        sm_ += cm[i]; st_ += ct[i]; sr_ += cr[i];
    }
    float s1 = 0.f, s2 = 0.f, sw = 0.f;
    for (int i = threadIdx.x; i < nk; i += 256) {
        s1 += k1p[i]; s2 += k2p[i]; sw += wp[i];
    }

    __shared__ float sh[4][6];
    float vals[6] = {sm_, st_, sr_, s1, s2, sw};
    #pragma unroll
    for (int k = 0; k < 6; ++k) vals[k] = wave_reduce_sum(vals[k]);
    const int wave = threadIdx.x >> 6;
    const int lane = threadIdx.x & 63;
    if (lane == 0) {
        #pragma unroll
        for (int k = 0; k < 6; ++k) sh[wave][k] = vals[k];
    }
    __syncthreads();

    if (threadIdx.x == 0) {
        float t[6];
        #pragma unroll
        for (int k = 0; k < 6; ++k)
            t[k] = sh[0][k] + sh[1][k] + sh[2][k] + sh[3][k];

        const float invBV = 1.f / ((float)NROWS * (float)NCOLS);
        const float BCE_merged = -t[0] * invBV;
        const float BCE_text   = -t[1] * invBV;
        const float BCE_rec    = -t[2] * invBV;
        const float BCE = (BCE_merged + BCE_text + BCE_rec) * (1.f / 3.f);

        const float invBD = 1.f / ((float)NROWS * (float)DDIM);
        const float KLD1 = -0.5f * t[3] * invBD;
        const float KLD2 = -0.5f * t[4] * invBD;
        const float wass = t[5] / (float)NROWS;

        const float l = BCE + 0.5f * (KLD1 + KLD2) + wass;

        out[0] = l;
        out[1] = BCE;
        out[2] = wass;
        out[3] = BCE_rec;
        out[4] = BCE_text;
        out[5] = BCE_merged;
    }
}

extern "C" void kernel_launch(void* const* d_in, const int* in_sizes, int n_in,
                              void* d_out, int out_size, void* d_ws, size_t ws_size,
                              hipStream_t stream) {
    const float4* recon_x      = (const float4*)d_in[0];
    const float4* logits_rec   = (const float4*)d_in[1];
    const float4* logits_text  = (const float4*)d_in[2];
    const float4* x            = (const float4*)d_in[3];
    const float4* mu           = (const float4*)d_in[4];
    const float4* logvar       = (const float4*)d_in[5];
    const float4* prior_mu     = (const float4*)d_in[6];
    const float4* prior_logvar = (const float4*)d_in[7];

    float* ws = (float*)d_ws;
    float* cm = ws;                 // [4096]
    float* ct = ws + NROWS;         // [4096]
    float* cr = ws + 2 * NROWS;     // [4096]
    const int NK = 512;
    float* k1p = ws + 3 * NROWS;            // [512]
    float* k2p = ws + 3 * NROWS + NK;       // [512]
    float* wp  = ws + 3 * NROWS + 2 * NK;   // [512]

    hipLaunchKernelGGL(kld_wass_kernel, dim3(NK), dim3(256), 0, stream,
                       mu, logvar, prior_mu, prior_logvar, k1p, k2p, wp);
    hipLaunchKernelGGL(bce_rows_kernel, dim3(NROWS), dim3(256), 0, stream,
                       recon_x, logits_rec, logits_text, x, cm, ct, cr);
    hipLaunchKernelGGL(finalize_kernel, dim3(1), dim3(256), 0, stream,
                       cm, ct, cr, k1p, k2p, wp, NK, (float*)d_out);
}

// Round 2
// 128.868 us; speedup vs baseline: 1.0361x; 1.0361x over previous
//
#include <hip/hip_runtime.h>

#define NROWS 4096
#define NCOLS 10000
#define DDIM  512
#define NKLD  256          // kld blocks (grid prefix)

__device__ __forceinline__ float wave_reduce_sum(float v) {
    #pragma unroll
    for (int o = 32; o > 0; o >>= 1) v += __shfl_down(v, o, 64);
    return v;
}

// ---------- fused kernel: blocks [0,NKLD) = KLD/Wasserstein, blocks [NKLD, NKLD+NROWS) = BCE rows ----------
__global__ __launch_bounds__(256) void fused_main_kernel(
    const float4* __restrict__ merged,  // recon_x
    const float4* __restrict__ rec,     // logits_rec
    const float4* __restrict__ text,    // logits_text
    const float4* __restrict__ xr,      // x
    const float4* __restrict__ mu, const float4* __restrict__ lv,
    const float4* __restrict__ pmu, const float4* __restrict__ plv,
    float* __restrict__ cm, float* __restrict__ ct, float* __restrict__ cr,
    float* __restrict__ k1o, float* __restrict__ k2o, float* __restrict__ wo)
{
    const int wave = threadIdx.x >> 6;
    const int lane = threadIdx.x & 63;

    if (blockIdx.x < NKLD) {
        // ----- KLD + Wasserstein partials (grid-stride over [B,D]) -----
        const int nvec = NROWS * DDIM / 4;   // 524288
        float k1 = 0.f, k2 = 0.f, wacc = 0.f;

        for (int i = blockIdx.x * 256 + threadIdx.x; i < nvec; i += NKLD * 256) {
            const float4 m  = mu[i];
            const float4 l  = lv[i];
            const float4 pm = pmu[i];
            const float4 pl = plv[i];

            #define KW_COMP(c)                                              \
            {                                                               \
                const float e1 = __expf(l.c);                               \
                const float e2 = __expf(pl.c);                              \
                k1 += 1.f + l.c - m.c * m.c - e1;                           \
                k2 += 1.f + pl.c - pm.c * pm.c - e2;                        \
                const float dm = m.c - pm.c;                                \
                wacc += dm * dm + e1 + e2 - 2.f * __expf(0.5f * (l.c + pl.c)); \
            }
            KW_COMP(x) KW_COMP(y) KW_COMP(z) KW_COMP(w)
            #undef KW_COMP
        }

        __shared__ float sm[4][3];
        k1 = wave_reduce_sum(k1);
        k2 = wave_reduce_sum(k2);
        wacc = wave_reduce_sum(wacc);
        if (lane == 0) { sm[wave][0] = k1; sm[wave][1] = k2; sm[wave][2] = wacc; }
        __syncthreads();
        if (threadIdx.x == 0) {
            k1o[blockIdx.x] = sm[0][0] + sm[1][0] + sm[2][0] + sm[3][0];
            k2o[blockIdx.x] = sm[0][1] + sm[1][1] + sm[2][1] + sm[3][1];
            wo[blockIdx.x]  = sm[0][2] + sm[1][2] + sm[2][2] + sm[3][2];
        }
        return;
    }

    // ----- BCE row: c_L = dot(L,x) - log(sum exp L) * sum x -----
    const int row = blockIdx.x - NKLD;
    const int nvec = NCOLS / 4;              // 2500 float4 per row
    const size_t base = (size_t)row * nvec;

    float se_m = 0.f, se_t = 0.f, se_r = 0.f;
    float d_m = 0.f, d_t = 0.f, d_r = 0.f;
    float sx = 0.f;

    #define BCE_BODY(xv, mv, tv, rv)                                          \
    {                                                                         \
        se_m += __expf(mv.x) + __expf(mv.y) + __expf(mv.z) + __expf(mv.w);    \
        se_t += __expf(tv.x) + __expf(tv.y) + __expf(tv.z) + __expf(tv.w);    \
        se_r += __expf(rv.x) + __expf(rv.y) + __expf(rv.z) + __expf(rv.w);    \
        d_m += mv.x * xv.x + mv.y * xv.y + mv.z * xv.z + mv.w * xv.w;         \
        d_t += tv.x * xv.x + tv.y * xv.y + tv.z * xv.z + tv.w * xv.w;         \
        d_r += rv.x * xv.x + rv.y * xv.y + rv.z * xv.z + rv.w * xv.w;         \
        sx  += xv.x + xv.y + xv.z + xv.w;                                     \
    }

    int i = threadIdx.x;
    // 2-way unrolled main loop: 8 clustered float4 loads (128 B in flight / thread)
    for (; i + 256 < nvec; i += 512) {
        const float4 xv0 = xr[base + i];
        const float4 mv0 = merged[base + i];
        const float4 tv0 = text[base + i];
        const float4 rv0 = rec[base + i];
        const float4 xv1 = xr[base + i + 256];
        const float4 mv1 = merged[base + i + 256];
        const float4 tv1 = text[base + i + 256];
        const float4 rv1 = rec[base + i + 256];
        BCE_BODY(xv0, mv0, tv0, rv0)
        BCE_BODY(xv1, mv1, tv1, rv1)
    }
    for (; i < nvec; i += 256) {
        const float4 xv = xr[base + i];
        const float4 mv = merged[base + i];
        const float4 tv = text[base + i];
        const float4 rv = rec[base + i];
        BCE_BODY(xv, mv, tv, rv)
    }
    #undef BCE_BODY

    __shared__ float sm2[4][7];
    float vals[7] = {se_m, se_t, se_r, d_m, d_t, d_r, sx};
    #pragma unroll
    for (int k = 0; k < 7; ++k) vals[k] = wave_reduce_sum(vals[k]);
    if (lane == 0) {
        #pragma unroll
        for (int k = 0; k < 7; ++k) sm2[wave][k] = vals[k];
    }
    __syncthreads();

    if (threadIdx.x == 0) {
        float t[7];
        #pragma unroll
        for (int k = 0; k < 7; ++k)
            t[k] = sm2[0][k] + sm2[1][k] + sm2[2][k] + sm2[3][k];
        const float sumx = t[6];
        cm[row] = t[3] - __logf(t[0]) * sumx;
        ct[row] = t[4] - __logf(t[1]) * sumx;
        cr[row] = t[5] - __logf(t[2]) * sumx;
    }
}

// ---------- finalize ----------
__global__ __launch_bounds__(256) void finalize_kernel(
    const float* __restrict__ cm, const float* __restrict__ ct,
    const float* __restrict__ cr, const float* __restrict__ k1p,
    const float* __restrict__ k2p, const float* __restrict__ wp,
    float* __restrict__ out)
{
    float sm_ = 0.f, st_ = 0.f, sr_ = 0.f;
    for (int i = threadIdx.x; i < NROWS; i += 256) {
        sm_ += cm[i]; st_ += ct[i]; sr_ += cr[i];
    }
    float s1 = 0.f, s2 = 0.f, sw = 0.f;
    for (int i = threadIdx.x; i < NKLD; i += 256) {
        s1 += k1p[i]; s2 += k2p[i]; sw += wp[i];
    }

    __shared__ float sh[4][6];
    float vals[6] = {sm_, st_, sr_, s1, s2, sw};
    #pragma unroll
    for (int k = 0; k < 6; ++k) vals[k] = wave_reduce_sum(vals[k]);
    const int wave = threadIdx.x >> 6;
    const int lane = threadIdx.x & 63;
    if (lane == 0) {
        #pragma unroll
        for (int k = 0; k < 6; ++k) sh[wave][k] = vals[k];
    }
    __syncthreads();

    if (threadIdx.x == 0) {
        float t[6];
        #pragma unroll
        for (int k = 0; k < 6; ++k)
            t[k] = sh[0][k] + sh[1][k] + sh[2][k] + sh[3][k];

        const float invBV = 1.f / ((float)NROWS * (float)NCOLS);
        const float BCE_merged = -t[0] * invBV;
        const float BCE_text   = -t[1] * invBV;
        const float BCE_rec    = -t[2] * invBV;
        const float BCE = (BCE_merged + BCE_text + BCE_rec) * (1.f / 3.f);

        const float invBD = 1.f / ((float)NROWS * (float)DDIM);
        const float KLD1 = -0.5f * t[3] * invBD;
        const float KLD2 = -0.5f * t[4] * invBD;
        const float wass = t[5] / (float)NROWS;

        const float l = BCE + 0.5f * (KLD1 + KLD2) + wass;

        out[0] = l;
        out[1] = BCE;
        out[2] = wass;
        out[3] = BCE_rec;
        out[4] = BCE_text;
        out[5] = BCE_merged;
    }
}

extern "C" void kernel_launch(void* const* d_in, const int* in_sizes, int n_in,
                              void* d_out, int out_size, void* d_ws, size_t ws_size,
                              hipStream_t stream) {
    const float4* recon_x      = (const float4*)d_in[0];
    const float4* logits_rec   = (const float4*)d_in[1];
    const float4* logits_text  = (const float4*)d_in[2];
    const float4* x            = (const float4*)d_in[3];
    const float4* mu           = (const float4*)d_in[4];
    const float4* logvar       = (const float4*)d_in[5];
    const float4* prior_mu     = (const float4*)d_in[6];
    const float4* prior_logvar = (const float4*)d_in[7];

    float* ws = (float*)d_ws;
    float* cm = ws;                           // [4096]
    float* ct = ws + NROWS;                   // [4096]
    float* cr = ws + 2 * NROWS;               // [4096]
    float* k1p = ws + 3 * NROWS;              // [256]
    float* k2p = ws + 3 * NROWS + NKLD;       // [256]
    float* wp  = ws + 3 * NROWS + 2 * NKLD;   // [256]

    hipLaunchKernelGGL(fused_main_kernel, dim3(NKLD + NROWS), dim3(256), 0, stream,
                       recon_x, logits_rec, logits_text, x,
                       mu, logvar, prior_mu, prior_logvar,
                       cm, ct, cr, k1p, k2p, wp);
    hipLaunchKernelGGL(finalize_kernel, dim3(1), dim3(256), 0, stream,
                       cm, ct, cr, k1p, k2p, wp, (float*)d_out);
}

// Round 3
// 128.809 us; speedup vs baseline: 1.0366x; 1.0005x over previous
//
#include <hip/hip_runtime.h>

#define NROWS 4096
#define NCOLS 10000
#define DDIM  512
#define NKLD  256          // kld blocks (grid prefix)

__device__ __forceinline__ float wave_reduce_sum(float v) {
    #pragma unroll
    for (int o = 32; o > 0; o >>= 1) v += __shfl_down(v, o, 64);
    return v;
}

// ---------- fused kernel: blocks [0,NKLD) = KLD/Wasserstein, blocks [NKLD, NKLD+NROWS) = BCE rows ----------
__global__ __launch_bounds__(256) void fused_main_kernel(
    const float4* __restrict__ merged,  // recon_x
    const float4* __restrict__ rec,     // logits_rec
    const float4* __restrict__ text,    // logits_text
    const float4* __restrict__ xr,      // x
    const float4* __restrict__ mu, const float4* __restrict__ lv,
    const float4* __restrict__ pmu, const float4* __restrict__ plv,
    float* __restrict__ cm, float* __restrict__ ct, float* __restrict__ cr,
    float* __restrict__ k1o, float* __restrict__ k2o, float* __restrict__ wo)
{
    const int wave = threadIdx.x >> 6;
    const int lane = threadIdx.x & 63;

    if (blockIdx.x < NKLD) {
        // ----- KLD + Wasserstein partials (grid-stride over [B,D]), 2-way unrolled -----
        const int nvec = NROWS * DDIM / 4;   // 524288 (divisible by NKLD*256*2)
        float k1 = 0.f, k2 = 0.f, wacc = 0.f;

        #define KW_BODY(m, l, pm, pl)                                       \
        {                                                                   \
            _Pragma("unroll")                                               \
            for (int c = 0; c < 4; ++c) {                                   \
                const float lc  = ((const float*)&l)[c];                    \
                const float plc = ((const float*)&pl)[c];                   \
                const float mc  = ((const float*)&m)[c];                    \
                const float pmc = ((const float*)&pm)[c];                   \
                const float e1 = __expf(lc);                                \
                const float e2 = __expf(plc);                               \
                k1 += 1.f + lc - mc * mc - e1;                              \
                k2 += 1.f + plc - pmc * pmc - e2;                           \
                const float dm = mc - pmc;                                  \
                wacc += dm * dm + e1 + e2 - 2.f * __expf(0.5f * (lc + plc));\
            }                                                               \
        }

        const int stride = NKLD * 256;
        for (int i = blockIdx.x * 256 + threadIdx.x; i < nvec; i += 2 * stride) {
            const float4 m0  = mu[i];
            const float4 l0  = lv[i];
            const float4 pm0 = pmu[i];
            const float4 pl0 = plv[i];
            const float4 m1  = mu[i + stride];
            const float4 l1  = lv[i + stride];
            const float4 pm1 = pmu[i + stride];
            const float4 pl1 = plv[i + stride];
            KW_BODY(m0, l0, pm0, pl0)
            KW_BODY(m1, l1, pm1, pl1)
        }
        #undef KW_BODY

        __shared__ float sm[4][3];
        k1 = wave_reduce_sum(k1);
        k2 = wave_reduce_sum(k2);
        wacc = wave_reduce_sum(wacc);
        if (lane == 0) { sm[wave][0] = k1; sm[wave][1] = k2; sm[wave][2] = wacc; }
        __syncthreads();
        if (threadIdx.x == 0) {
            k1o[blockIdx.x] = sm[0][0] + sm[1][0] + sm[2][0] + sm[3][0];
            k2o[blockIdx.x] = sm[0][1] + sm[1][1] + sm[2][1] + sm[3][1];
            wo[blockIdx.x]  = sm[0][2] + sm[1][2] + sm[2][2] + sm[3][2];
        }
        return;
    }

    // ----- BCE row: c_L = dot(L,x) - log(sum exp L) * sum x -----
    const int row = blockIdx.x - NKLD;
    const int nvec = NCOLS / 4;              // 2500 float4 per row
    const size_t base = (size_t)row * nvec;

    float se_m = 0.f, se_t = 0.f, se_r = 0.f;
    float d_m = 0.f, d_t = 0.f, d_r = 0.f;
    float sx = 0.f;

    #define BCE_BODY(xv, mv, tv, rv)                                          \
    {                                                                         \
        se_m += __expf(mv.x) + __expf(mv.y) + __expf(mv.z) + __expf(mv.w);    \
        se_t += __expf(tv.x) + __expf(tv.y) + __expf(tv.z) + __expf(tv.w);    \
        se_r += __expf(rv.x) + __expf(rv.y) + __expf(rv.z) + __expf(rv.w);    \
        d_m += mv.x * xv.x + mv.y * xv.y + mv.z * xv.z + mv.w * xv.w;         \
        d_t += tv.x * xv.x + tv.y * xv.y + tv.z * xv.z + tv.w * xv.w;         \
        d_r += rv.x * xv.x + rv.y * xv.y + rv.z * xv.z + rv.w * xv.w;         \
        sx  += xv.x + xv.y + xv.z + xv.w;                                     \
    }

    int i = threadIdx.x;
    // 3-way unrolled main loop: 12 clustered float4 loads (192 B in flight / thread)
    for (; i + 512 < nvec; i += 768) {
        const float4 xv0 = xr[base + i];
        const float4 xv1 = xr[base + i + 256];
        const float4 xv2 = xr[base + i + 512];
        const float4 mv0 = merged[base + i];
        const float4 mv1 = merged[base + i + 256];
        const float4 mv2 = merged[base + i + 512];
        const float4 tv0 = text[base + i];
        const float4 tv1 = text[base + i + 256];
        const float4 tv2 = text[base + i + 512];
        const float4 rv0 = rec[base + i];
        const float4 rv1 = rec[base + i + 256];
        const float4 rv2 = rec[base + i + 512];
        BCE_BODY(xv0, mv0, tv0, rv0)
        BCE_BODY(xv1, mv1, tv1, rv1)
        BCE_BODY(xv2, mv2, tv2, rv2)
    }
    for (; i < nvec; i += 256) {
        const float4 xv = xr[base + i];
        const float4 mv = merged[base + i];
        const float4 tv = text[base + i];
        const float4 rv = rec[base + i];
        BCE_BODY(xv, mv, tv, rv)
    }
    #undef BCE_BODY

    __shared__ float sm2[4][7];
    float vals[7] = {se_m, se_t, se_r, d_m, d_t, d_r, sx};
    #pragma unroll
    for (int k = 0; k < 7; ++k) vals[k] = wave_reduce_sum(vals[k]);
    if (lane == 0) {
        #pragma unroll
        for (int k = 0; k < 7; ++k) sm2[wave][k] = vals[k];
    }
    __syncthreads();

    if (threadIdx.x == 0) {
        float t[7];
        #pragma unroll
        for (int k = 0; k < 7; ++k)
            t[k] = sm2[0][k] + sm2[1][k] + sm2[2][k] + sm2[3][k];
        const float sumx = t[6];
        cm[row] = t[3] - __logf(t[0]) * sumx;
        ct[row] = t[4] - __logf(t[1]) * sumx;
        cr[row] = t[5] - __logf(t[2]) * sumx;
    }
}

// ---------- finalize ----------
__global__ __launch_bounds__(256) void finalize_kernel(
    const float* __restrict__ cm, const float* __restrict__ ct,
    const float* __restrict__ cr, const float* __restrict__ k1p,
    const float* __restrict__ k2p, const float* __restrict__ wp,
    float* __restrict__ out)
{
    float sm_ = 0.f, st_ = 0.f, sr_ = 0.f;
    for (int i = threadIdx.x; i < NROWS; i += 256) {
        sm_ += cm[i]; st_ += ct[i]; sr_ += cr[i];
    }
    float s1 = 0.f, s2 = 0.f, sw = 0.f;
    for (int i = threadIdx.x; i < NKLD; i += 256) {
        s1 += k1p[i]; s2 += k2p[i]; sw += wp[i];
    }

    __shared__ float sh[4][6];
    float vals[6] = {sm_, st_, sr_, s1, s2, sw};
    #pragma unroll
    for (int k = 0; k < 6; ++k) vals[k] = wave_reduce_sum(vals[k]);
    const int wave = threadIdx.x >> 6;
    const int lane = threadIdx.x & 63;
    if (lane == 0) {
        #pragma unroll
        for (int k = 0; k < 6; ++k) sh[wave][k] = vals[k];
    }
    __syncthreads();

    if (threadIdx.x == 0) {
        float t[6];
        #pragma unroll
        for (int k = 0; k < 6; ++k)
            t[k] = sh[0][k] + sh[1][k] + sh[2][k] + sh[3][k];

        const float invBV = 1.f / ((float)NROWS * (float)NCOLS);
        const float BCE_merged = -t[0] * invBV;
        const float BCE_text   = -t[1] * invBV;
        const float BCE_rec    = -t[2] * invBV;
        const float BCE = (BCE_merged + BCE_text + BCE_rec) * (1.f / 3.f);

        const float invBD = 1.f / ((float)NROWS * (float)DDIM);
        const float KLD1 = -0.5f * t[3] * invBD;
        const float KLD2 = -0.5f * t[4] * invBD;
        const float wass = t[5] / (float)NROWS;

        const float l = BCE + 0.5f * (KLD1 + KLD2) + wass;

        out[0] = l;
        out[1] = BCE;
        out[2] = wass;
        out[3] = BCE_rec;
        out[4] = BCE_text;
        out[5] = BCE_merged;
    }
}

extern "C" void kernel_launch(void* const* d_in, const int* in_sizes, int n_in,
                              void* d_out, int out_size, void* d_ws, size_t ws_size,
                              hipStream_t stream) {
    const float4* recon_x      = (const float4*)d_in[0];
    const float4* logits_rec   = (const float4*)d_in[1];
    const float4* logits_text  = (const float4*)d_in[2];
    const float4* x            = (const float4*)d_in[3];
    const float4* mu           = (const float4*)d_in[4];
    const float4* logvar       = (const float4*)d_in[5];
    const float4* prior_mu     = (const float4*)d_in[6];
    const float4* prior_logvar = (const float4*)d_in[7];

    float* ws = (float*)d_ws;
    float* cm = ws;                           // [4096]
    float* ct = ws + NROWS;                   // [4096]
    float* cr = ws + 2 * NROWS;               // [4096]
    float* k1p = ws + 3 * NROWS;              // [256]
    float* k2p = ws + 3 * NROWS + NKLD;       // [256]
    float* wp  = ws + 3 * NROWS + 2 * NKLD;   // [256]

    hipLaunchKernelGGL(fused_main_kernel, dim3(NKLD + NROWS), dim3(256), 0, stream,
                       recon_x, logits_rec, logits_text, x,
                       mu, logvar, prior_mu, prior_logvar,
                       cm, ct, cr, k1p, k2p, wp);
    hipLaunchKernelGGL(finalize_kernel, dim3(1), dim3(256), 0, stream,
                       cm, ct, cr, k1p, k2p, wp, (float*)d_out);
}

// Round 4
// 127.062 us; speedup vs baseline: 1.0508x; 1.0137x over previous
//
#include <hip/hip_runtime.h>

#define NROWS 4096
#define NCOLS 10000
#define DDIM  512
#define NBLK  2048         // one resident generation: 8 blocks/CU x 256 CU

__device__ __forceinline__ float wave_reduce_sum(float v) {
    #pragma unroll
    for (int o = 32; o > 0; o >>= 1) v += __shfl_down(v, o, 64);
    return v;
}

// Each block: one 256-float4 KLD/Wasserstein slice + two full BCE rows.
// Writes per-block partials: k1p/k2p/wp[b], cm/ct/cr[b] (sum over its 2 rows).
__global__ __launch_bounds__(256) void fused_main_kernel(
    const float4* __restrict__ merged,  // recon_x
    const float4* __restrict__ rec,     // logits_rec
    const float4* __restrict__ text,    // logits_text
    const float4* __restrict__ xr,      // x
    const float4* __restrict__ mu, const float4* __restrict__ lv,
    const float4* __restrict__ pmu, const float4* __restrict__ plv,
    float* __restrict__ cm, float* __restrict__ ct, float* __restrict__ cr,
    float* __restrict__ k1o, float* __restrict__ k2o, float* __restrict__ wo)
{
    const int wave = threadIdx.x >> 6;
    const int lane = threadIdx.x & 63;

    // ---------- KLD + Wasserstein slice: exactly 1 float4 per tensor per thread ----------
    float k1 = 0.f, k2 = 0.f, wacc = 0.f;
    {
        const int i = blockIdx.x * 256 + threadIdx.x;   // < 524288 always
        const float4 m  = mu[i];
        const float4 l  = lv[i];
        const float4 pm = pmu[i];
        const float4 pl = plv[i];
        #pragma unroll
        for (int c = 0; c < 4; ++c) {
            const float lc  = ((const float*)&l)[c];
            const float plc = ((const float*)&pl)[c];
            const float mc  = ((const float*)&m)[c];
            const float pmc = ((const float*)&pm)[c];
            const float e1 = __expf(lc);
            const float e2 = __expf(plc);
            k1 += 1.f + lc - mc * mc - e1;
            k2 += 1.f + plc - pmc * pmc - e2;
            const float dm = mc - pmc;
            wacc += dm * dm + e1 + e2 - 2.f * __expf(0.5f * (lc + plc));
        }
    }

    // ---------- two BCE rows ----------
    // c_L(row) = dot(L_row, x_row) - log(sum exp L_row) * sum x_row
    const int nvec = NCOLS / 4;              // 2500 float4 per row
    float acc_m = 0.f, acc_t = 0.f, acc_r = 0.f;   // c sums over the 2 rows (thread 0 only)
    __shared__ float sm2[4][7];

    #pragma unroll
    for (int half = 0; half < 2; ++half) {
        const int row = blockIdx.x * 2 + half;
        const size_t base = (size_t)row * nvec;

        float se_m = 0.f, se_t = 0.f, se_r = 0.f;
        float d_m = 0.f, d_t = 0.f, d_r = 0.f;
        float sx = 0.f;

        #define BCE_BODY(xv, mv, tv, rv)                                          \
        {                                                                         \
            se_m += __expf(mv.x) + __expf(mv.y) + __expf(mv.z) + __expf(mv.w);    \
            se_t += __expf(tv.x) + __expf(tv.y) + __expf(tv.z) + __expf(tv.w);    \
            se_r += __expf(rv.x) + __expf(rv.y) + __expf(rv.z) + __expf(rv.w);    \
            d_m += mv.x * xv.x + mv.y * xv.y + mv.z * xv.z + mv.w * xv.w;         \
            d_t += tv.x * xv.x + tv.y * xv.y + tv.z * xv.z + tv.w * xv.w;         \
            d_r += rv.x * xv.x + rv.y * xv.y + rv.z * xv.z + rv.w * xv.w;         \
            sx  += xv.x + xv.y + xv.z + xv.w;                                     \
        }

        int i = threadIdx.x;
        // 3-way unrolled: 12 clustered float4 loads (192 B in flight / thread)
        for (; i + 512 < nvec; i += 768) {
            const float4 xv0 = xr[base + i];
            const float4 xv1 = xr[base + i + 256];
            const float4 xv2 = xr[base + i + 512];
            const float4 mv0 = merged[base + i];
            const float4 mv1 = merged[base + i + 256];
            const float4 mv2 = merged[base + i + 512];
            const float4 tv0 = text[base + i];
            const float4 tv1 = text[base + i + 256];
            const float4 tv2 = text[base + i + 512];
            const float4 rv0 = rec[base + i];
            const float4 rv1 = rec[base + i + 256];
            const float4 rv2 = rec[base + i + 512];
            BCE_BODY(xv0, mv0, tv0, rv0)
            BCE_BODY(xv1, mv1, tv1, rv1)
            BCE_BODY(xv2, mv2, tv2, rv2)
        }
        for (; i < nvec; i += 256) {
            const float4 xv = xr[base + i];
            const float4 mv = merged[base + i];
            const float4 tv = text[base + i];
            const float4 rv = rec[base + i];
            BCE_BODY(xv, mv, tv, rv)
        }
        #undef BCE_BODY

        float vals[7] = {se_m, se_t, se_r, d_m, d_t, d_r, sx};
        #pragma unroll
        for (int k = 0; k < 7; ++k) vals[k] = wave_reduce_sum(vals[k]);
        if (lane == 0) {
            #pragma unroll
            for (int k = 0; k < 7; ++k) sm2[wave][k] = vals[k];
        }
        __syncthreads();
        if (threadIdx.x == 0) {
            float t[7];
            #pragma unroll
            for (int k = 0; k < 7; ++k)
                t[k] = sm2[0][k] + sm2[1][k] + sm2[2][k] + sm2[3][k];
            const float sumx = t[6];
            acc_m += t[3] - __logf(t[0]) * sumx;
            acc_t += t[4] - __logf(t[1]) * sumx;
            acc_r += t[5] - __logf(t[2]) * sumx;
        }
        __syncthreads();   // sm2 reuse safety for half=1
    }

    // ---------- per-block outputs ----------
    {
        __shared__ float smk[4][3];
        k1 = wave_reduce_sum(k1);
        k2 = wave_reduce_sum(k2);
        wacc = wave_reduce_sum(wacc);
        if (lane == 0) { smk[wave][0] = k1; smk[wave][1] = k2; smk[wave][2] = wacc; }
        __syncthreads();
        if (threadIdx.x == 0) {
            k1o[blockIdx.x] = smk[0][0] + smk[1][0] + smk[2][0] + smk[3][0];
            k2o[blockIdx.x] = smk[0][1] + smk[1][1] + smk[2][1] + smk[3][1];
            wo[blockIdx.x]  = smk[0][2] + smk[1][2] + smk[2][2] + smk[3][2];
            cm[blockIdx.x] = acc_m;
            ct[blockIdx.x] = acc_t;
            cr[blockIdx.x] = acc_r;
        }
    }
}

// ---------- finalize: 6 x 2048 partials -> 6 scalars ----------
__global__ __launch_bounds__(256) void finalize_kernel(
    const float* __restrict__ cm, const float* __restrict__ ct,
    const float* __restrict__ cr, const float* __restrict__ k1p,
    const float* __restrict__ k2p, const float* __restrict__ wp,
    float* __restrict__ out)
{
    float v[6] = {0.f, 0.f, 0.f, 0.f, 0.f, 0.f};
    for (int i = threadIdx.x; i < NBLK; i += 256) {
        v[0] += cm[i]; v[1] += ct[i]; v[2] += cr[i];
        v[3] += k1p[i]; v[4] += k2p[i]; v[5] += wp[i];
    }

    __shared__ float sh[4][6];
    #pragma unroll
    for (int k = 0; k < 6; ++k) v[k] = wave_reduce_sum(v[k]);
    const int wave = threadIdx.x >> 6;
    const int lane = threadIdx.x & 63;
    if (lane == 0) {
        #pragma unroll
        for (int k = 0; k < 6; ++k) sh[wave][k] = v[k];
    }
    __syncthreads();

    if (threadIdx.x == 0) {
        float t[6];
        #pragma unroll
        for (int k = 0; k < 6; ++k)
            t[k] = sh[0][k] + sh[1][k] + sh[2][k] + sh[3][k];

        const float invBV = 1.f / ((float)NROWS * (float)NCOLS);
        const float BCE_merged = -t[0] * invBV;
        const float BCE_text   = -t[1] * invBV;
        const float BCE_rec    = -t[2] * invBV;
        const float BCE = (BCE_merged + BCE_text + BCE_rec) * (1.f / 3.f);

        const float invBD = 1.f / ((float)NROWS * (float)DDIM);
        const float KLD1 = -0.5f * t[3] * invBD;
        const float KLD2 = -0.5f * t[4] * invBD;
        const float wass = t[5] / (float)NROWS;

        const float l = BCE + 0.5f * (KLD1 + KLD2) + wass;

        out[0] = l;
        out[1] = BCE;
        out[2] = wass;
        out[3] = BCE_rec;
        out[4] = BCE_text;
        out[5] = BCE_merged;
    }
}

extern "C" void kernel_launch(void* const* d_in, const int* in_sizes, int n_in,
                              void* d_out, int out_size, void* d_ws, size_t ws_size,
                              hipStream_t stream) {
    const float4* recon_x      = (const float4*)d_in[0];
    const float4* logits_rec   = (const float4*)d_in[1];
    const float4* logits_text  = (const float4*)d_in[2];
    const float4* x            = (const float4*)d_in[3];
    const float4* mu           = (const float4*)d_in[4];
    const float4* logvar      = (const float4*)d_in[5];
    const float4* prior_mu     = (const float4*)d_in[6];
    const float4* prior_logvar = (const float4*)d_in[7];

    float* ws = (float*)d_ws;
    float* cm  = ws;                 // [2048]
    float* ct  = ws + NBLK;          // [2048]
    float* cr  = ws + 2 * NBLK;      // [2048]
    float* k1p = ws + 3 * NBLK;      // [2048]
    float* k2p = ws + 4 * NBLK;      // [2048]
    float* wp  = ws + 5 * NBLK;      // [2048]

    hipLaunchKernelGGL(fused_main_kernel, dim3(NBLK), dim3(256), 0, stream,
                       recon_x, logits_rec, logits_text, x,
                       mu, logvar, prior_mu, prior_logvar,
                       cm, ct, cr, k1p, k2p, wp);
    hipLaunchKernelGGL(finalize_kernel, dim3(1), dim3(256), 0, stream,
                       cm, ct, cr, k1p, k2p, wp, (float*)d_out);
}